// Round 1
// baseline (372.810 us; speedup 1.0000x reference)
//
#include <hip/hip_runtime.h>
#include <hip/hip_bf16.h>
#include <math.h>

// Problem constants
#define NB      65536
#define DD      15
#define NFQ     199
#define DTC     0.05f
#define INV_NORM (1.0f/150.0f)
#define PH_SCALE 1.2566370614359172f   // 2*pi / T_PERIOD
#define KTAY    12                      // Taylor terms for expm(DT*L) action
#define KTAY_U  30                      // Taylor terms for u = expm(i*theta)

// ---------------------------------------------------------------------------
// Kernel 1: u = expm(i*theta), theta = (u_re+u_re^T) + i(u_im-u_im^T)
// M = i*theta is skew-Hermitian (norm <~ 2.7) -> plain Taylor is stable.
// Output: ws_u[2*(a*15+b)] = Re(u[a][b]), +1 = Im.
// ---------------------------------------------------------------------------
__global__ __launch_bounds__(256) void k_u(const float* __restrict__ u_re,
                                           const float* __restrict__ u_im,
                                           float* __restrict__ ws_u) {
    __shared__ float Mre[225], Mim[225], cre[225], cim[225], are[225], aim[225];
    int tid = threadIdx.x;
    if (tid < 225) {
        int a = tid / 15, b = tid % 15;
        float tre = u_re[a*15+b] + u_re[b*15+a];   // Re(theta)
        float tim = u_im[a*15+b] - u_im[b*15+a];   // Im(theta)
        Mre[tid] = -tim;                            // Re(i*theta)
        Mim[tid] =  tre;                            // Im(i*theta)
        float id = (a == b) ? 1.0f : 0.0f;
        cre[tid] = id; cim[tid] = 0.0f;
        are[tid] = id; aim[tid] = 0.0f;
    }
    __syncthreads();
    for (int k = 1; k <= KTAY_U; ++k) {
        float nre = 0.0f, nim = 0.0f;
        if (tid < 225) {
            int a = tid / 15, b = tid % 15;
            for (int j = 0; j < 15; ++j) {
                float mre = Mre[a*15+j], mim = Mim[a*15+j];
                float xre = cre[j*15+b], xim = cim[j*15+b];
                nre += mre*xre - mim*xim;
                nim += mre*xim + mim*xre;
            }
            float inv = 1.0f / (float)k;
            nre *= inv; nim *= inv;
        }
        __syncthreads();
        if (tid < 225) {
            cre[tid] = nre; cim[tid] = nim;
            are[tid] += nre; aim[tid] += nim;
        }
        __syncthreads();
    }
    if (tid < 225) {
        ws_u[2*tid]   = are[tid];
        ws_u[2*tid+1] = aim[tid];
    }
}

// ---------------------------------------------------------------------------
// Kernel 2: transposed, amp-folded weight table: wt[n][64]
//   [0..14]  = w_g[m][n]*amp_g[n]         [15] = freqs_g[n]
//   [16..30] = w_g[m][199+n]*amp_g[199+n] [31] = 0
//   [32..46] = w_o[m][n]*amp_o[n]         [47] = freqs_o[n]
//   [48..62] = w_o[m][199+n]*amp_o[199+n] [63] = 0
// ---------------------------------------------------------------------------
__global__ __launch_bounds__(64) void k_wt(const float* __restrict__ fg, const float* __restrict__ ag,
                                           const float* __restrict__ wg,
                                           const float* __restrict__ fo, const float* __restrict__ ao,
                                           const float* __restrict__ wo,
                                           float* __restrict__ wt) {
    int n = blockIdx.x, t = threadIdx.x;
    float v;
    if (t < 15)       v = wg[t*398 + n]            * ag[n];
    else if (t == 15) v = fg[n];
    else if (t < 31)  v = wg[(t-16)*398 + 199 + n] * ag[199 + n];
    else if (t == 31) v = 0.0f;
    else if (t < 47)  v = wo[(t-32)*398 + n]       * ao[n];
    else if (t == 47) v = fo[n];
    else if (t < 63)  v = wo[(t-48)*398 + 199 + n] * ao[199 + n];
    else              v = 0.0f;
    wt[n*64 + t] = v;
}

// ---------------------------------------------------------------------------
// Kernel 3: 30 basis matrices of L, layout Lb[c*512 + r*32 + g] = basis_g[r][c]
//   g in 0..14  : gamma basis  A_p  (dsx part + tr_id column)
//   g = 15      : zero
//   g in 16..30 : omega basis  B_k  (h_comm = -4 f[k,i,j])
//   g = 31      : zero
// A_p[m,n] = -8*( sum_{jk} f[m,j,k]*FR[n,k,j]  +  sum_{ik} f[m,i,k]*DI[n,k,i] )
//   FR[n,k,j] = sum_i f[n,i,k]*R_p[i,j],  DI[n,k,i] = sum_j d[n,j,k]*I_p[i,j]
// col_p[m] = 4*sum_{ij} f[i,m,j]*I_p[i,j]
// ---------------------------------------------------------------------------
__global__ __launch_bounds__(256) void k_basis(const float* __restrict__ f,
                                               const float* __restrict__ dten,
                                               const float* __restrict__ ws_u,
                                               float* __restrict__ Lb) {
    int p = blockIdx.x;
    int tid = threadIdx.x;
    int c = tid >> 4, r = tid & 15;

    if (p == 15) {  // zero-pad slices g=15, g=31
        Lb[c*512 + r*32 + 15] = 0.0f;
        Lb[c*512 + r*32 + 31] = 0.0f;
        return;
    }

    __shared__ float fs[3375], dsh[3375];
    __shared__ float Rm[225], Im[225];
    __shared__ float FR[3375], DI[3375];
    __shared__ float accA[225], colv[15];
    __shared__ float su_re[15], su_im[15];

    for (int idx = tid; idx < 3375; idx += 256) {
        fs[idx]  = f[idx];
        dsh[idx] = dten[idx];
    }
    if (tid < 15) {
        su_re[tid] = ws_u[2*(tid*15 + p)];
        su_im[tid] = ws_u[2*(tid*15 + p) + 1];
    }
    __syncthreads();

    if (tid < 225) {
        int i = tid / 15, j = tid % 15;
        Rm[tid] = su_re[i]*su_re[j] + su_im[i]*su_im[j];   // Re(u_ip * conj(u_jp))
        Im[tid] = su_im[i]*su_re[j] - su_re[i]*su_im[j];   // Im(u_ip * conj(u_jp))
    }
    __syncthreads();

    for (int idx = tid; idx < 3375; idx += 256) {
        int n  = idx / 225;
        int rm = idx % 225;
        int k  = rm / 15;
        int j  = rm % 15;   // FR index j; DI index i
        float s1 = 0.0f, s2 = 0.0f;
        for (int i = 0; i < 15; ++i) s1 += fs[(n*15+i)*15 + k] * Rm[i*15 + j];
        for (int jj = 0; jj < 15; ++jj) s2 += dsh[(n*15+jj)*15 + k] * Im[j*15 + jj];
        FR[idx] = s1;
        DI[idx] = s2;  // DI[n][k][i] with i==j slot
    }
    __syncthreads();

    if (tid < 225) {
        int m = tid / 15, n = tid % 15;
        float a1 = 0.0f, x = 0.0f;
        for (int j = 0; j < 15; ++j)
            for (int k = 0; k < 15; ++k)
                a1 += fs[(m*15+j)*15 + k] * FR[n*225 + k*15 + j];
        for (int i = 0; i < 15; ++i)
            for (int k = 0; k < 15; ++k)
                x  += fs[(m*15+i)*15 + k] * DI[n*225 + k*15 + i];
        accA[tid] = -8.0f * (a1 + x);
    }
    if (tid < 15) {
        int m = tid;
        float s = 0.0f;
        for (int i = 0; i < 15; ++i)
            for (int j = 0; j < 15; ++j)
                s += fs[(i*15+m)*15 + j] * Im[i*15 + j];
        colv[m] = 4.0f * s;
    }
    __syncthreads();

    float vg, vo;
    if (r == 0)      { vg = 0.0f;                          vo = 0.0f; }
    else if (c == 0) { vg = colv[r-1];                     vo = 0.0f; }
    else             { vg = accA[(r-1)*15 + (c-1)];
                       vo = -4.0f * fs[(p*15 + (r-1))*15 + (c-1)]; }
    Lb[c*512 + r*32 + p]      = vg;
    Lb[c*512 + r*32 + 16 + p] = vo;
}

// ---------------------------------------------------------------------------
// Kernel 4: per-sample coefficients gamma/omega -> coef[s][32]
//   [0..14] gamma, [15]=0, [16..30] omega, [31]=0
// ---------------------------------------------------------------------------
__global__ __launch_bounds__(256) void k_coef(const float* __restrict__ t,
                                              const float* __restrict__ bg,
                                              const float* __restrict__ bo,
                                              const float* __restrict__ wt,
                                              float* __restrict__ coef) {
    int s = blockIdx.x * 256 + threadIdx.x;
    float ph = t[s] * PH_SCALE;
    float gp[15], op[15];
#pragma unroll
    for (int m = 0; m < 15; ++m) { gp[m] = 0.0f; op[m] = 0.0f; }

    for (int n = 0; n < NFQ; ++n) {
        const float4* row = (const float4*)(wt + n*64);
        float h[32];
        float s_, c_;
#pragma unroll
        for (int j = 0; j < 8; ++j) *(float4*)&h[4*j] = row[j];
        __sincosf(ph * h[15], &s_, &c_);
#pragma unroll
        for (int m = 0; m < 15; ++m) gp[m] += c_*h[m] + s_*h[16+m];
#pragma unroll
        for (int j = 0; j < 8; ++j) *(float4*)&h[4*j] = row[8+j];
        __sincosf(ph * h[15], &s_, &c_);
#pragma unroll
        for (int m = 0; m < 15; ++m) op[m] += c_*h[m] + s_*h[16+m];
    }

    float ob[32];
#pragma unroll
    for (int m = 0; m < 15; ++m) {
        float g1 = gp[m] + bg[m];
        ob[m]      = g1 * g1 * INV_NORM;
        ob[16+m]   = (op[m] + bo[m]) * INV_NORM;
    }
    ob[15] = 0.0f; ob[31] = 0.0f;
    float* dst = coef + (size_t)s * 32;
#pragma unroll
    for (int j = 0; j < 8; ++j) *(float4*)(dst + 4*j) = *(float4*)&ob[4*j];
}

// ---------------------------------------------------------------------------
// Kernel 5: main — build L row per thread (16 threads/sample), Taylor action.
// out[s][j] = ( expm(DT*L) [1;x] )[1+j]
// ---------------------------------------------------------------------------
__global__ __launch_bounds__(256) void k_main(const float* __restrict__ x,
                                              const float* __restrict__ coef,
                                              const float* __restrict__ Lbw,
                                              float* __restrict__ out) {
    __shared__ float Lb[16*16*36];          // [c][r][36] (pad 36 kills bank conflicts)
    __shared__ float wbuf[2][16][16];       // [buf][group][r]
    int tid = threadIdx.x;

    // preload basis into LDS: [c][r][32] -> [c][r][36]
    {
        int c = tid >> 4, r = tid & 15;
        const float4* src = (const float4*)(Lbw + c*512 + r*32);
        float* dst = &Lb[c*576 + r*36];
#pragma unroll
        for (int j = 0; j < 8; ++j) *(float4*)(dst + 4*j) = src[j];
    }
    __syncthreads();

    int gi = tid >> 4, r = tid & 15;
    int s = blockIdx.x * 16 + gi;

    // load 32 coefficients (broadcast within group)
    float cf[32];
    {
        const float4* cp = (const float4*)(coef + (size_t)s * 32);
#pragma unroll
        for (int j = 0; j < 8; ++j) {
            float4 v = cp[j];
            cf[4*j] = v.x; cf[4*j+1] = v.y; cf[4*j+2] = v.z; cf[4*j+3] = v.w;
        }
    }

    // build my row of L
    float Lrow[16];
#pragma unroll
    for (int c = 0; c < 16; ++c) {
        float acc = 0.0f;
        const float* lb = &Lb[c*576 + r*36];
#pragma unroll
        for (int j = 0; j < 8; ++j) {
            float4 v = *(const float4*)(lb + 4*j);
            acc += v.x*cf[4*j] + v.y*cf[4*j+1] + v.z*cf[4*j+2] + v.w*cf[4*j+3];
        }
        Lrow[c] = acc;
    }

    // Taylor action: w0 = [1; x], acc = sum_k (DT*L)^k/k! * w0
    float w = (r == 0) ? 1.0f : x[(size_t)s*15 + (r-1)];
    float acc = w;
#pragma unroll
    for (int k = 1; k <= KTAY; ++k) {
        wbuf[k & 1][gi][r] = w;
        __syncthreads();
        const float* wp = &wbuf[k & 1][gi][0];
        float nw = 0.0f;
#pragma unroll
        for (int j = 0; j < 4; ++j) {
            float4 v = *(const float4*)(wp + 4*j);
            nw += Lrow[4*j]*v.x + Lrow[4*j+1]*v.y + Lrow[4*j+2]*v.z + Lrow[4*j+3]*v.w;
        }
        w = nw * (DTC / (float)k);
        acc += w;
    }

    if (r > 0) out[(size_t)s*15 + (r-1)] = acc;
}

// ---------------------------------------------------------------------------
extern "C" void kernel_launch(void* const* d_in, const int* in_sizes, int n_in,
                              void* d_out, int out_size, void* d_ws, size_t ws_size,
                              hipStream_t stream) {
    const float* t    = (const float*)d_in[0];
    const float* x    = (const float*)d_in[1];
    const float* u_re = (const float*)d_in[2];
    const float* u_im = (const float*)d_in[3];
    const float* fg   = (const float*)d_in[4];
    const float* ag   = (const float*)d_in[5];
    const float* wg   = (const float*)d_in[6];
    const float* bg   = (const float*)d_in[7];
    const float* fo   = (const float*)d_in[8];
    const float* ao   = (const float*)d_in[9];
    const float* wo   = (const float*)d_in[10];
    const float* bo   = (const float*)d_in[11];
    const float* f    = (const float*)d_in[12];
    const float* dten = (const float*)d_in[13];
    float* out = (float*)d_out;
    float* ws  = (float*)d_ws;

    float* u_ws = ws;                 // 450 floats (rounded to 512)
    float* Lbw  = ws + 512;           // 16*16*32 = 8192 floats
    float* wt   = ws + 8704;          // 199*64 = 12736 floats
    float* coef = ws + 21440;         // 65536*32 floats (~8 MB)

    hipLaunchKernelGGL(k_u,     dim3(1),    dim3(256), 0, stream, u_re, u_im, u_ws);
    hipLaunchKernelGGL(k_wt,    dim3(199),  dim3(64),  0, stream, fg, ag, wg, fo, ao, wo, wt);
    hipLaunchKernelGGL(k_basis, dim3(16),   dim3(256), 0, stream, f, dten, u_ws, Lbw);
    hipLaunchKernelGGL(k_coef,  dim3(256),  dim3(256), 0, stream, t, bg, bo, wt, coef);
    hipLaunchKernelGGL(k_main,  dim3(4096), dim3(256), 0, stream, x, coef, Lbw, out);
}